// Round 1
// baseline (596.495 us; speedup 1.0000x reference)
//
#include <hip/hip_runtime.h>

#define MARGIN 0.1f
#define BB 256
#define CC 4096
#define DD 100
#define TPB 256            // threads per block
#define ROWS 256           // c-rows per block (must equal TPB for the epilogue)
#define F4_PER_ROW (DD / 4)               // 25 float4 per row
#define ITERS (ROWS * F4_PER_ROW / TPB)   // 25 coalesced iterations

// Coalesced streaming version.
// Grid = (CC/ROWS, BB) = (16, 256). Each block owns 256 consecutive rows of
// one b. The 256 threads read the block's 100 KB of neg data as 25 fully
// coalesced float4 loads (16 B lane stride), compute the per-float4 squared
// distance against the LDS-staged pos row, and accumulate per-row sums with
// LDS float atomics (each row gets 25 adds spread across banks -> negligible).
// Epilogue: thread tid owns row tid -> hinge -> block reduce -> 1 atomicAdd.
__global__ __launch_bounds__(TPB) void amloss_kernel(const float* __restrict__ pos,
                                                     const float* __restrict__ neg,
                                                     const float* __restrict__ lan,
                                                     float* __restrict__ out) {
    const int tid = threadIdx.x;
    const int b   = blockIdx.y;
    const int c0  = blockIdx.x * ROWS;

    __shared__ __align__(16) float pos_s[DD];
    __shared__ float rowsum[ROWS];

    rowsum[tid] = 0.f;                       // ROWS == TPB
    if (tid < DD) pos_s[tid] = pos[b * DD + tid];
    __syncthreads();

    const float4* __restrict__ nblk =
        (const float4*)(neg + ((size_t)b * CC + (size_t)c0) * DD);
    const float4* __restrict__ pos4 = (const float4*)pos_s;

    #pragma unroll 5
    for (int it = 0; it < ITERS; ++it) {
        const int g   = it * TPB + tid;      // float4 index within block tile
        const int row = g / F4_PER_ROW;      // magic-mul div by 25
        const int j   = g - row * F4_PER_ROW;
        const float4 v = nblk[g];            // coalesced: 16 B lane stride
        const float4 p = pos4[j];            // LDS gather, <=4-way conflict
        const float d0 = p.x - v.x;
        const float d1 = p.y - v.y;
        const float d2 = p.z - v.z;
        const float d3 = p.w - v.w;
        atomicAdd(&rowsum[row], d0 * d0 + d1 * d1 + d2 * d2 + d3 * d3);
    }
    __syncthreads();

    // Thread tid owns row tid.
    float contrib = fmaxf(MARGIN - rowsum[tid] * (1.f / (float)DD), 0.f)
                  * (1.f / ((float)BB * (float)CC));

    // Fused loss1: one block-column (blockIdx.x==0) per b handles 100 elems.
    if (blockIdx.x == 0 && tid < DD) {
        const float d = pos_s[tid] - lan[b * DD + tid];
        contrib += d * d * (1.f / ((float)BB * (float)DD));
    }

    // Block reduction: butterfly within wave, LDS across the 4 waves.
    #pragma unroll
    for (int off = 32; off >= 1; off >>= 1)
        contrib += __shfl_xor(contrib, off, 64);
    __shared__ float ws[TPB / 64];
    if ((tid & 63) == 0) ws[tid >> 6] = contrib;
    __syncthreads();
    if (tid == 0) atomicAdd(out, ws[0] + ws[1] + ws[2] + ws[3]);
}

extern "C" void kernel_launch(void* const* d_in, const int* in_sizes, int n_in,
                              void* d_out, int out_size, void* d_ws, size_t ws_size,
                              hipStream_t stream) {
    const float* pos = (const float*)d_in[0];
    const float* neg = (const float*)d_in[1];
    const float* lan = (const float*)d_in[2];
    float* out = (float*)d_out;

    // Zero-init output (harness re-poisons to 0xAA); graph-capturable memset.
    hipMemsetAsync(out, 0, (size_t)out_size * sizeof(float), stream);

    amloss_kernel<<<dim3(CC / ROWS, BB), TPB, 0, stream>>>(pos, neg, lan, out);
}

// Round 2
// 573.130 us; speedup vs baseline: 1.0408x; 1.0408x over previous
//
#include <hip/hip_runtime.h>

#define MARGIN 0.1f
#define BB 256
#define CC 4096
#define DD 100
#define TPB 256   // threads per block; grid = (CC/TPB, BB)

// One thread per (b, c) pair. Each thread reads its 400 B neg row as 25
// aligned float4 loads, accumulates the squared distance privately (no
// cross-lane traffic in the hot loop), applies the hinge, and the block
// reduces once at the end -> one atomicAdd per block.
//
// Memory-access note (round-1 post-mortem): a wave's 64 lanes cover 64
// CONSECUTIVE rows = one contiguous 25.6 KB span that fits in the 32 KiB L1.
// The 400 B-strided dwordx4 gathers therefore fetch each cache line exactly
// once and reuse it across the 25 unrolled iterations — L1-blocked streaming
// at HBM rate (~60 us for the 419.5 MB of neg, vs 64 us pure-HBM floor at
// the 6.5 TB/s the harness's own fill dispatches achieve). An explicitly
// coalesced LDS-atomic variant measured ~38% SLOWER (LDS atomic-RMW throttle).
// Blocks with blockIdx.x == 0 additionally fold in their b's slice of loss1.
__global__ __launch_bounds__(TPB) void amloss_kernel(const float* __restrict__ pos,
                                                     const float* __restrict__ neg,
                                                     const float* __restrict__ lan,
                                                     float* __restrict__ out) {
    const int tid = threadIdx.x;
    const int b   = blockIdx.y;
    const int c   = blockIdx.x * TPB + tid;

    // Stage pos[b,:] once; hot-loop reads are wave-uniform broadcasts (free).
    __shared__ __align__(16) float pos_s[DD];
    if (tid < DD) pos_s[tid] = pos[b * DD + tid];
    __syncthreads();

    const float4* __restrict__ row =
        (const float4*)(neg + ((size_t)b * CC + (size_t)c) * DD);
    const float4* __restrict__ pos4 = (const float4*)pos_s;

    float s = 0.f;
    #pragma unroll
    for (int k = 0; k < DD / 4; ++k) {
        const float4 v = row[k];
        const float4 p = pos4[k];   // ds_read_b128 broadcast
        const float d0 = p.x - v.x;
        const float d1 = p.y - v.y;
        const float d2 = p.z - v.z;
        const float d3 = p.w - v.w;
        s += d0 * d0 + d1 * d1 + d2 * d2 + d3 * d3;
    }
    float contrib = fmaxf(MARGIN - s * (1.f / (float)DD), 0.f)
                  * (1.f / ((float)BB * (float)CC));

    // Fused loss1: one block-column (blockIdx.x==0) per b handles 100 elems.
    if (blockIdx.x == 0 && tid < DD) {
        const float d = pos_s[tid] - lan[b * DD + tid];
        contrib += d * d * (1.f / ((float)BB * (float)DD));
    }

    // Block reduction: butterfly within wave, LDS across the 4 waves.
    #pragma unroll
    for (int off = 32; off >= 1; off >>= 1)
        contrib += __shfl_xor(contrib, off, 64);
    __shared__ float ws[4];
    if ((tid & 63) == 0) ws[tid >> 6] = contrib;
    __syncthreads();
    if (tid == 0) atomicAdd(out, ws[0] + ws[1] + ws[2] + ws[3]);
}

extern "C" void kernel_launch(void* const* d_in, const int* in_sizes, int n_in,
                              void* d_out, int out_size, void* d_ws, size_t ws_size,
                              hipStream_t stream) {
    const float* pos = (const float*)d_in[0];
    const float* neg = (const float*)d_in[1];
    const float* lan = (const float*)d_in[2];
    float* out = (float*)d_out;

    // Zero-init output (harness re-poisons to 0xAA); graph-capturable memset.
    hipMemsetAsync(out, 0, (size_t)out_size * sizeof(float), stream);

    amloss_kernel<<<dim3(CC / TPB, BB), TPB, 0, stream>>>(pos, neg, lan, out);
}